// Round 17
// baseline (225.441 us; speedup 1.0000x reference)
//
#include <hip/hip_runtime.h>

#define NN 50000
#define NP 50048  // padded to multiple of 64
#define NE 800000
#define ET (NE + NN)
#define NB 196              // coarse buckets (dst>>8)
#define CAP 8192            // per-bucket capacity (avg 4337, +58 sigma)
#define P1_B ((ET + 1023) / 1024)     // 831
#define CONVW_B 32                    // 32768 / 1024
#define CONVX_B (NP * 32 / 1024)      // 1564 (exact)
#define FRONT_B (P1_B + CONVW_B + CONVX_B)
#define GEMM_B (NP / 64)              // 782
#define MID_B (NB + GEMM_B)           // 978

typedef __attribute__((ext_vector_type(8))) short short8;
typedef __attribute__((ext_vector_type(4))) float f32x4;

static __device__ __forceinline__ float bf2f(unsigned short u) {
  union { unsigned int i; float f; } v; v.i = ((unsigned int)u) << 16; return v.f;
}
static __device__ __forceinline__ unsigned short f2bf(float f) {
  union { unsigned int i; float f; } v; v.f = f;
  unsigned int r = v.i + 0x7fffu + ((v.i >> 16) & 1u);
  return (unsigned short)(r >> 16);
}
static __device__ __forceinline__ float lrelu(float z) { return z > 0.f ? z : 0.2f * z; }

// ---------------- fused front (1024 thr): p1 (CSR bucket) | conv_w | conv_x ----------------
__global__ __launch_bounds__(1024) void k_front(
    const int* __restrict__ ei, int* __restrict__ gcount, int* __restrict__ tmp,
    const float* __restrict__ W1, unsigned short* __restrict__ wh,
    const float* __restrict__ x, unsigned short* __restrict__ xh) {
  __shared__ int hist[NB];
  __shared__ int lbase[NB];
  const int b = blockIdx.x;
  const int tid = threadIdx.x;
  if (b < P1_B) {
    if (tid < NB) hist[tid] = 0;
    __syncthreads();
    int e = b * 1024 + tid;
    bool valid = (e < ET);
    int src = 0, dst = 0, bk = 0, loc = 0;
    if (valid) {
      src = (e < NE) ? ei[e] : (e - NE);
      dst = (e < NE) ? ei[NE + e] : (e - NE);
      bk = dst >> 8;
      loc = atomicAdd(&hist[bk], 1);  // LDS atomic
    }
    __syncthreads();
    if (tid < NB) {
      int c = hist[tid];
      lbase[tid] = (c > 0) ? atomicAdd(&gcount[tid], c) : 0;
    }
    __syncthreads();
    if (valid) tmp[bk * CAP + lbase[bk] + loc] = (src << 8) | (dst & 255);
  } else if (b < P1_B + CONVW_B) {
    int i = (b - P1_B) * 1024 + tid;  // i < 32768
    int k = i >> 8, n = i & 255;
    wh[n * 128 + k] = f2bf(W1[i]);
  } else {
    int i4 = (b - P1_B - CONVW_B) * 1024 + tid;  // i4 < NP*32 exactly
    int i = i4 * 4;
    int row = i >> 7;
    float4 v = (row < NN) ? *(const float4*)(x + i) : (float4){0.f, 0.f, 0.f, 0.f};
    ushort4 h;
    h.x = f2bf(v.x);
    h.y = f2bf(v.y);
    h.z = f2bf(v.z);
    h.w = f2bf(v.w);
    *(ushort4*)(xh + i) = h;
  }
}

// ---------------- fused mid (256 thr): p2 (counting sort) | gemm1 (bf16 MFMA) ----------------
__global__ __launch_bounds__(256) void k_mid(
    const int* __restrict__ tmp, const int* __restrict__ gcount,
    int* __restrict__ ssrc, int* __restrict__ row_ptr,
    const unsigned short* __restrict__ xh, const unsigned short* __restrict__ wh,
    const float* __restrict__ a1s, const float* __restrict__ a1d,
    unsigned short* __restrict__ h1, float* __restrict__ as1, float* __restrict__ ad1) {
  __shared__ unsigned short hst[64][264];  // 33792 B; p2 path aliases into it
  const int tid = threadIdx.x;
  if (blockIdx.x < NB) {
    int* hist = (int*)&hst[0][0];
    int* sa = hist + 256;
    int* sb = sa + 256;
    int* cur = sb + 256;
    int* base_sh = cur + 256;
    const int t = tid;
    const int b = blockIdx.x;
    const int n_b = gcount[b];
    sa[t] = (t < NB) ? gcount[t] : 0;
    __syncthreads();
    {
      int* s = sa;
      int* d = sb;
      for (int off = 1; off < 256; off <<= 1) {
        int v = s[t];
        if (t >= off) v += s[t - off];
        d[t] = v;
        int* tm = s; s = d; d = tm;
        __syncthreads();
      }
      if (t == 0) {
        base_sh[0] = (b == 0) ? 0 : s[b - 1];
        if (b == 0) row_ptr[NN] = ET;
      }
    }
    hist[t] = 0;
    __syncthreads();
    const int base = base_sh[0];
    for (int i = t; i < n_b; i += 256) {
      int p = tmp[b * CAP + i];
      atomicAdd(&hist[p & 255], 1);
    }
    __syncthreads();
    sa[t] = hist[t];
    __syncthreads();
    {
      int* s = sa;
      int* d = sb;
      for (int off = 1; off < 256; off <<= 1) {
        int v = s[t];
        if (t >= off) v += s[t - off];
        d[t] = v;
        int* tm = s; s = d; d = tm;
        __syncthreads();
      }
      int excl = (t == 0) ? 0 : s[t - 1];
      int start = base + excl;
      cur[t] = start;
      int d_glob = (b << 8) + t;
      if (d_glob < NN) row_ptr[d_glob] = start;
    }
    __syncthreads();
    for (int i = t; i < n_b; i += 256) {
      int p = tmp[b * CAP + i];
      int pos = atomicAdd(&cur[p & 255], 1);  // LDS cursor
      ssrc[pos] = p >> 8;
    }
    return;
  }
  // ---- gemm1: single-pass bf16 MFMA ----
  const int gb = blockIdx.x - NB;
  const int w = tid >> 6, lane = tid & 63;
  const int quad = lane >> 4, m16 = lane & 15;
  const int row0 = gb * 64;
  const int koff = quad * 8;

  f32x4 acc[4][4];
  for (int mt = 0; mt < 4; ++mt)
    for (int nt = 0; nt < 4; ++nt) acc[mt][nt] = (f32x4){0.f, 0.f, 0.f, 0.f};

  for (int kt = 0; kt < 4; ++kt) {
    short8 ah[4], bh[4];
    for (int mt = 0; mt < 4; ++mt) {
      size_t ra = (size_t)(row0 + mt * 16 + m16) * 128 + kt * 32 + koff;
      ah[mt] = *(const short8*)(xh + ra);
    }
    for (int nt = 0; nt < 4; ++nt) {
      size_t rb = (size_t)(w * 64 + nt * 16 + m16) * 128 + kt * 32 + koff;
      bh[nt] = *(const short8*)(wh + rb);
    }
    for (int mt = 0; mt < 4; ++mt)
      for (int nt = 0; nt < 4; ++nt)
        acc[mt][nt] = __builtin_amdgcn_mfma_f32_16x16x32_bf16(ah[mt], bh[nt], acc[mt][nt], 0, 0, 0);
  }
  for (int mt = 0; mt < 4; ++mt)
    for (int nt = 0; nt < 4; ++nt) {
      int c = w * 64 + nt * 16 + m16;
      int rb = mt * 16 + quad * 4;
      for (int r = 0; r < 4; ++r) hst[rb + r][c] = f2bf(acc[mt][nt][r]);
    }
  __syncthreads();
  for (int p = 0; p < 8; ++p) {
    int idx = p * 256 + tid;
    int row = idx >> 5, u4 = idx & 31;
    int grow = row0 + row;
    if (grow < NN) {
      uint4 v = *(const uint4*)&hst[row][u4 * 8];
      *(uint4*)(h1 + (size_t)grow * 256 + u4 * 8) = v;
    }
  }
  for (int p = 0; p < 2; ++p) {
    int id = p * 256 + tid;
    int row = id >> 3, head = id & 7;
    int grow = row0 + row;
    if (grow < NN) {
      float sa = 0.f, sd = 0.f;
      for (int c = 0; c < 32; ++c) {
        float hv = bf2f(hst[row][head * 32 + c]);
        sa = fmaf(hv, a1s[head * 32 + c], sa);
        sd = fmaf(hv, a1d[head * 32 + c], sd);
      }
      as1[(size_t)grow * 8 + head] = sa;
      ad1[(size_t)grow * 8 + head] = sd;
    }
  }
}

// ---------------- Layer-1 aggregation: fused pass, uint4 gathers (2 edges per load-instr) ----------------
// Phase-2 lane mapping: p = lane>>5 (edge pair-half), q = lane&31, hB = q>>2, cq = q&3.
// Lane owns channels [hB*32 + cq*8, +8) of its half's edge; halves merged via shfl_xor(32).
__global__ __launch_bounds__(256) void k_agg1(
    const int* __restrict__ row_ptr, const int* __restrict__ ssrc,
    const unsigned short* __restrict__ h1, const float* __restrict__ as1,
    const float* __restrict__ ad1, const float* __restrict__ b1,
    const float* __restrict__ W2, const float* __restrict__ a2s,
    const float* __restrict__ a2d, float4* __restrict__ nd) {
  const int lane = threadIdx.x & 63;
  const int dst = (int)((blockIdx.x * blockDim.x + threadIdx.x) >> 6);
  if (dst >= NN) return;  // wave-uniform
  const int start = row_ptr[dst], end = row_ptr[dst + 1];
  const int hA = lane & 7;
  const int eoff = lane >> 3;
  const int p = lane >> 5;           // pair half
  const int q = lane & 31;
  const int hB = q >> 2;             // head
  const int cq = q & 3;              // channel quad (8 ch)
  const float ad_h = ad1[(size_t)dst * 8 + hA];
  float s_loc = 0.f;
  float acc[8];
#pragma unroll
  for (int c = 0; c < 8; ++c) acc[c] = 0.f;
  for (int base = start; base < end; base += 16) {
    int ea = base + eoff, eb = base + 8 + eoff;
    int sa_ = 0, sb_ = 0;
    float wa = 0.f, wb = 0.f;
    if (ea < end) {
      sa_ = ssrc[ea];
      wa = __expf(lrelu(as1[(size_t)sa_ * 8 + hA] + ad_h));
    }
    if (eb < end) {
      sb_ = ssrc[eb];
      wb = __expf(lrelu(as1[(size_t)sb_ * 8 + hA] + ad_h));
    }
    s_loc += wa + wb;
    uint4 u[8];
    float w8[8];
#pragma unroll
    for (int j = 0; j < 8; ++j) {
      int se0 = __shfl(sa_, j * 8);
      int se1 = __shfl(sb_, j * 8);
      float w0 = __shfl(wa, j * 8 + hB);
      float w1 = __shfl(wb, j * 8 + hB);
      int se = p ? se1 : se0;
      w8[j] = p ? w1 : w0;
      u[j] = *(const uint4*)(h1 + (size_t)se * 256 + hB * 32 + cq * 8);
    }
#pragma unroll
    for (int j = 0; j < 8; ++j) {
      float w = w8[j];
      const unsigned int qq[4] = {u[j].x, u[j].y, u[j].z, u[j].w};
#pragma unroll
      for (int c = 0; c < 4; ++c) {
        acc[2 * c] = fmaf(w, bf2f((unsigned short)(qq[c] & 0xffffu)), acc[2 * c]);
        acc[2 * c + 1] = fmaf(w, bf2f((unsigned short)(qq[c] >> 16)), acc[2 * c + 1]);
      }
    }
  }
  // merge the two pair-halves
#pragma unroll
  for (int c = 0; c < 8; ++c) acc[c] += __shfl_xor(acc[c], 32);
  // softmax denominator (phase-1 mapping): reduce over edge-groups
  s_loc += __shfl_xor(s_loc, 8);
  s_loc += __shfl_xor(s_loc, 16);
  s_loc += __shfl_xor(s_loc, 32);
  const float inv_s = 1.f / (s_loc + 1e-16f);
  const float inv_sB = __shfl(inv_s, hB);  // lane hB holds s for head hB (its hA == hB)
  // epilogue: +b1, ELU, @W2 (256->2) over this lane's 8 channels
  float tp0 = 0.f, tp1 = 0.f;
#pragma unroll
  for (int c = 0; c < 8; ++c) {
    int col = hB * 32 + cq * 8 + c;
    float v = acc[c] * inv_sB + b1[col];
    v = v > 0.f ? v : (__expf(v) - 1.f);  // ELU
    float2 w2 = *(const float2*)(W2 + col * 2);
    tp0 = fmaf(v, w2.x, tp0);
    tp1 = fmaf(v, w2.y, tp1);
  }
  // sum over the 32 (hB,cq) lanes within each half (halves are identical)
  tp0 += __shfl_xor(tp0, 1);
  tp1 += __shfl_xor(tp1, 1);
  tp0 += __shfl_xor(tp0, 2);
  tp1 += __shfl_xor(tp1, 2);
  tp0 += __shfl_xor(tp0, 4);
  tp1 += __shfl_xor(tp1, 4);
  tp0 += __shfl_xor(tp0, 8);
  tp1 += __shfl_xor(tp1, 8);
  tp0 += __shfl_xor(tp0, 16);
  tp1 += __shfl_xor(tp1, 16);
  if (lane == 0) {
    float s2v = tp0 * a2s[0] + tp1 * a2s[1];
    float d2v = tp0 * a2d[0] + tp1 * a2d[1];
    nd[dst] = (float4){tp0, tp1, s2v, d2v};  // packed node table for agg2
  }
}

// ---------------- Layer-2 aggregation: 16 lanes per dst, packed float4 gathers ----------------
__global__ __launch_bounds__(256) void k_agg2(
    const int* __restrict__ row_ptr, const int* __restrict__ ssrc,
    const float4* __restrict__ nd, const float* __restrict__ b2,
    float* __restrict__ out) {
  int gid = blockIdx.x * 256 + threadIdx.x;
  int n = gid >> 4;
  int l16 = threadIdx.x & 15;
  if (n >= NN) return;
  int st = row_ptr[n], en = row_ptr[n + 1];
  float dv = nd[n].w;
  float ssum = 0.f, o0 = 0.f, o1 = 0.f;
  for (int e = st + l16; e < en; e += 16) {
    int s = ssrc[e];
    float4 v = nd[s];
    float w = __expf(lrelu(v.z + dv));
    ssum += w;
    o0 = fmaf(w, v.x, o0);
    o1 = fmaf(w, v.y, o1);
  }
  ssum += __shfl_xor(ssum, 1); o0 += __shfl_xor(o0, 1); o1 += __shfl_xor(o1, 1);
  ssum += __shfl_xor(ssum, 2); o0 += __shfl_xor(o0, 2); o1 += __shfl_xor(o1, 2);
  ssum += __shfl_xor(ssum, 4); o0 += __shfl_xor(o0, 4); o1 += __shfl_xor(o1, 4);
  ssum += __shfl_xor(ssum, 8); o0 += __shfl_xor(o0, 8); o1 += __shfl_xor(o1, 8);
  if (l16 == 0) {
    float inv = 1.f / (ssum + 1e-16f);
    out[(size_t)n * 2 + 0] = o0 * inv + b2[0];
    out[(size_t)n * 2 + 1] = o1 * inv + b2[1];
  }
}

extern "C" void kernel_launch(void* const* d_in, const int* in_sizes, int n_in,
                              void* d_out, int out_size, void* d_ws, size_t ws_size,
                              hipStream_t stream) {
  const float* x = (const float*)d_in[0];
  const int* ei = (const int*)d_in[1];
  // d_in[2] = batch (unused)
  const float* W1 = (const float*)d_in[3];
  const float* a1s = (const float*)d_in[4];
  const float* a1d = (const float*)d_in[5];
  const float* b1 = (const float*)d_in[6];
  const float* W2 = (const float*)d_in[7];
  const float* a2s = (const float*)d_in[8];
  const float* a2d = (const float*)d_in[9];
  const float* b2 = (const float*)d_in[10];
  float* out = (float*)d_out;

  char* ws = (char*)d_ws;
  size_t off = 0;
  auto alloc = [&](size_t bytes) -> void* {
    void* p = ws + off;
    off += (bytes + 255) & ~(size_t)255;
    return p;
  };
  int* gcount = (int*)alloc((size_t)NB * 4);
  int* tmp = (int*)alloc((size_t)NB * CAP * 4);
  int* row_ptr = (int*)alloc((size_t)(NN + 1) * 4);
  int* ssrc = (int*)alloc((size_t)ET * 4);
  unsigned short* xh = (unsigned short*)alloc((size_t)NP * 128 * 2);
  unsigned short* wh = (unsigned short*)alloc((size_t)32768 * 2);
  unsigned short* h1 = (unsigned short*)alloc((size_t)NN * 256 * 2);
  float* as1 = (float*)alloc((size_t)NN * 8 * 4);
  float* ad1 = (float*)alloc((size_t)NN * 8 * 4);
  float4* nd = (float4*)alloc((size_t)NN * 16);
  (void)ws_size; (void)in_sizes; (void)n_in; (void)out_size;

  hipMemsetAsync(gcount, 0, (size_t)NB * 4, stream);
  k_front<<<FRONT_B, 1024, 0, stream>>>(ei, gcount, tmp, W1, wh, x, xh);
  k_mid<<<MID_B, 256, 0, stream>>>(tmp, gcount, ssrc, row_ptr, xh, wh, a1s, a1d, h1, as1, ad1);
  k_agg1<<<(NN + 3) / 4, 256, 0, stream>>>(row_ptr, ssrc, h1, as1, ad1, b1, W2, a2s, a2d, nd);
  k_agg2<<<(NN * 16 + 255) / 256, 256, 0, stream>>>(row_ptr, ssrc, nd, b2, out);
}

// Round 18
// 208.303 us; speedup vs baseline: 1.0823x; 1.0823x over previous
//
#include <hip/hip_runtime.h>

#define NN 50000
#define NP 50048  // padded to multiple of 64
#define NE 800000
#define ET (NE + NN)
#define NB 196              // coarse buckets (dst>>8)
#define CAP 8192            // per-bucket capacity (avg 4337, +58 sigma)
#define EPB 4096            // edges per p1 block (4 per thread)
#define P1_B ((ET + EPB - 1) / EPB)   // 208
#define CONVW_B 32                    // 32768 / 1024
#define CONVX_B (NP * 32 / 1024)      // 1564 (exact)
#define FRONT_B (P1_B + CONVW_B + CONVX_B)
#define GEMM_B (NP / 64)              // 782
#define MID_B (NB + GEMM_B)           // 978

typedef __attribute__((ext_vector_type(8))) short short8;
typedef __attribute__((ext_vector_type(4))) float f32x4;

static __device__ __forceinline__ float bf2f(unsigned short u) {
  union { unsigned int i; float f; } v; v.i = ((unsigned int)u) << 16; return v.f;
}
static __device__ __forceinline__ unsigned short f2bf(float f) {
  union { unsigned int i; float f; } v; v.f = f;
  unsigned int r = v.i + 0x7fffu + ((v.i >> 16) & 1u);
  return (unsigned short)(r >> 16);
}
static __device__ __forceinline__ float lrelu(float z) { return z > 0.f ? z : 0.2f * z; }

// ---------------- fused front (1024 thr): p1 (CSR bucket, 4 edges/thread) | conv_w | conv_x ----------------
__global__ __launch_bounds__(1024) void k_front(
    const int* __restrict__ ei, int* __restrict__ gcount, int* __restrict__ tmp,
    const float* __restrict__ W1, unsigned short* __restrict__ wh,
    const float* __restrict__ x, unsigned short* __restrict__ xh) {
  __shared__ int hist[NB];
  __shared__ int lbase[NB];
  const int b = blockIdx.x;
  const int tid = threadIdx.x;
  if (b < P1_B) {
    if (tid < NB) hist[tid] = 0;
    __syncthreads();
    const int e0 = b * EPB + tid;
    int bkv[4], locv[4], pkv[4];
    bool val[4];
#pragma unroll
    for (int j = 0; j < 4; ++j) {
      int e = e0 + j * 1024;
      val[j] = (e < ET);
      int s = 0, d = 0;
      if (val[j]) {
        s = (e < NE) ? ei[e] : (e - NE);
        d = (e < NE) ? ei[NE + e] : (e - NE);
      }
      bkv[j] = d >> 8;
      pkv[j] = (s << 8) | (d & 255);
      locv[j] = val[j] ? atomicAdd(&hist[bkv[j]], 1) : 0;  // LDS atomic
    }
    __syncthreads();
    if (tid < NB) {
      int c = hist[tid];
      lbase[tid] = (c > 0) ? atomicAdd(&gcount[tid], c) : 0;
    }
    __syncthreads();
#pragma unroll
    for (int j = 0; j < 4; ++j)
      if (val[j]) tmp[bkv[j] * CAP + lbase[bkv[j]] + locv[j]] = pkv[j];
  } else if (b < P1_B + CONVW_B) {
    int i = (b - P1_B) * 1024 + tid;  // i < 32768
    int k = i >> 8, n = i & 255;
    wh[n * 128 + k] = f2bf(W1[i]);
  } else {
    int i4 = (b - P1_B - CONVW_B) * 1024 + tid;  // i4 < NP*32 exactly
    int i = i4 * 4;
    int row = i >> 7;
    float4 v = (row < NN) ? *(const float4*)(x + i) : (float4){0.f, 0.f, 0.f, 0.f};
    ushort4 h;
    h.x = f2bf(v.x);
    h.y = f2bf(v.y);
    h.z = f2bf(v.z);
    h.w = f2bf(v.w);
    *(ushort4*)(xh + i) = h;
  }
}

// ---------------- fused mid (256 thr): p2 (counting sort) | gemm1 (bf16 MFMA) ----------------
__global__ __launch_bounds__(256) void k_mid(
    const int* __restrict__ tmp, const int* __restrict__ gcount,
    int* __restrict__ ssrc, int* __restrict__ row_ptr,
    const unsigned short* __restrict__ xh, const unsigned short* __restrict__ wh,
    const float* __restrict__ a1s, const float* __restrict__ a1d,
    unsigned short* __restrict__ h1, float* __restrict__ as1, float* __restrict__ ad1) {
  __shared__ unsigned short hst[64][264];  // 33792 B; p2 path aliases into it
  const int tid = threadIdx.x;
  if (blockIdx.x < NB) {
    int* hist = (int*)&hst[0][0];
    int* sa = hist + 256;
    int* sb = sa + 256;
    int* cur = sb + 256;
    int* base_sh = cur + 256;
    const int t = tid;
    const int b = blockIdx.x;
    const int n_b = gcount[b];
    sa[t] = (t < NB) ? gcount[t] : 0;
    __syncthreads();
    {
      int* s = sa;
      int* d = sb;
      for (int off = 1; off < 256; off <<= 1) {
        int v = s[t];
        if (t >= off) v += s[t - off];
        d[t] = v;
        int* tm = s; s = d; d = tm;
        __syncthreads();
      }
      if (t == 0) {
        base_sh[0] = (b == 0) ? 0 : s[b - 1];
        if (b == 0) row_ptr[NN] = ET;
      }
    }
    hist[t] = 0;
    __syncthreads();
    const int base = base_sh[0];
    for (int i = t; i < n_b; i += 256) {
      int p = tmp[b * CAP + i];
      atomicAdd(&hist[p & 255], 1);
    }
    __syncthreads();
    sa[t] = hist[t];
    __syncthreads();
    {
      int* s = sa;
      int* d = sb;
      for (int off = 1; off < 256; off <<= 1) {
        int v = s[t];
        if (t >= off) v += s[t - off];
        d[t] = v;
        int* tm = s; s = d; d = tm;
        __syncthreads();
      }
      int excl = (t == 0) ? 0 : s[t - 1];
      int start = base + excl;
      cur[t] = start;
      int d_glob = (b << 8) + t;
      if (d_glob < NN) row_ptr[d_glob] = start;
    }
    __syncthreads();
    for (int i = t; i < n_b; i += 256) {
      int p = tmp[b * CAP + i];
      int pos = atomicAdd(&cur[p & 255], 1);  // LDS cursor
      ssrc[pos] = p >> 8;
    }
    return;
  }
  // ---- gemm1: single-pass bf16 MFMA ----
  const int gb = blockIdx.x - NB;
  const int w = tid >> 6, lane = tid & 63;
  const int quad = lane >> 4, m16 = lane & 15;
  const int row0 = gb * 64;
  const int koff = quad * 8;

  f32x4 acc[4][4];
  for (int mt = 0; mt < 4; ++mt)
    for (int nt = 0; nt < 4; ++nt) acc[mt][nt] = (f32x4){0.f, 0.f, 0.f, 0.f};

  for (int kt = 0; kt < 4; ++kt) {
    short8 ah[4], bh[4];
    for (int mt = 0; mt < 4; ++mt) {
      size_t ra = (size_t)(row0 + mt * 16 + m16) * 128 + kt * 32 + koff;
      ah[mt] = *(const short8*)(xh + ra);
    }
    for (int nt = 0; nt < 4; ++nt) {
      size_t rb = (size_t)(w * 64 + nt * 16 + m16) * 128 + kt * 32 + koff;
      bh[nt] = *(const short8*)(wh + rb);
    }
    for (int mt = 0; mt < 4; ++mt)
      for (int nt = 0; nt < 4; ++nt)
        acc[mt][nt] = __builtin_amdgcn_mfma_f32_16x16x32_bf16(ah[mt], bh[nt], acc[mt][nt], 0, 0, 0);
  }
  for (int mt = 0; mt < 4; ++mt)
    for (int nt = 0; nt < 4; ++nt) {
      int c = w * 64 + nt * 16 + m16;
      int rb = mt * 16 + quad * 4;
      for (int r = 0; r < 4; ++r) hst[rb + r][c] = f2bf(acc[mt][nt][r]);
    }
  __syncthreads();
  for (int p = 0; p < 8; ++p) {
    int idx = p * 256 + tid;
    int row = idx >> 5, u4 = idx & 31;
    int grow = row0 + row;
    if (grow < NN) {
      uint4 v = *(const uint4*)&hst[row][u4 * 8];
      *(uint4*)(h1 + (size_t)grow * 256 + u4 * 8) = v;
    }
  }
  for (int p = 0; p < 2; ++p) {
    int id = p * 256 + tid;
    int row = id >> 3, head = id & 7;
    int grow = row0 + row;
    if (grow < NN) {
      float sa = 0.f, sd = 0.f;
      for (int c = 0; c < 32; ++c) {
        float hv = bf2f(hst[row][head * 32 + c]);
        sa = fmaf(hv, a1s[head * 32 + c], sa);
        sd = fmaf(hv, a1d[head * 32 + c], sd);
      }
      as1[(size_t)grow * 8 + head] = sa;
      ad1[(size_t)grow * 8 + head] = sd;
    }
  }
}

// ---------------- Layer-1 aggregation: single fused pass, 16-edge batches (r16 proven form) ----------------
__global__ __launch_bounds__(256) void k_agg1(
    const int* __restrict__ row_ptr, const int* __restrict__ ssrc,
    const unsigned short* __restrict__ h1, const float* __restrict__ as1,
    const float* __restrict__ ad1, const float* __restrict__ b1,
    const float* __restrict__ W2, const float* __restrict__ a2s,
    const float* __restrict__ a2d, float4* __restrict__ nd) {
  const int lane = threadIdx.x & 63;
  const int dst = (int)((blockIdx.x * blockDim.x + threadIdx.x) >> 6);
  if (dst >= NN) return;  // wave-uniform
  const int start = row_ptr[dst], end = row_ptr[dst + 1];
  const int hA = lane & 7;
  const int eoff = lane >> 3;
  const int hB = lane >> 3;
  const int cB = (lane & 7) * 4;
  const float ad_h = ad1[(size_t)dst * 8 + hA];
  float s_loc = 0.f;
  float acc0 = 0.f, acc1 = 0.f, acc2 = 0.f, acc3 = 0.f;
  for (int base = start; base < end; base += 16) {
    int ea = base + eoff, eb = base + 8 + eoff;
    int sa_ = 0, sb_ = 0;
    float wa = 0.f, wb = 0.f;
    if (ea < end) {
      sa_ = ssrc[ea];
      wa = __expf(lrelu(as1[(size_t)sa_ * 8 + hA] + ad_h));
    }
    if (eb < end) {
      sb_ = ssrc[eb];
      wb = __expf(lrelu(as1[(size_t)sb_ * 8 + hA] + ad_h));
    }
    s_loc += wa + wb;
    uint2 u[16];
    float w16[16];
#pragma unroll
    for (int j = 0; j < 8; ++j) {
      int se = __shfl(sa_, j * 8);
      w16[j] = __shfl(wa, j * 8 + hB);
      u[j] = *(const uint2*)(h1 + (size_t)se * 256 + hB * 32 + cB);
    }
#pragma unroll
    for (int j = 0; j < 8; ++j) {
      int se = __shfl(sb_, j * 8);
      w16[8 + j] = __shfl(wb, j * 8 + hB);
      u[8 + j] = *(const uint2*)(h1 + (size_t)se * 256 + hB * 32 + cB);
    }
#pragma unroll
    for (int j = 0; j < 16; ++j) {
      float w = w16[j];
      acc0 = fmaf(w, bf2f((unsigned short)(u[j].x & 0xffffu)), acc0);
      acc1 = fmaf(w, bf2f((unsigned short)(u[j].x >> 16)), acc1);
      acc2 = fmaf(w, bf2f((unsigned short)(u[j].y & 0xffffu)), acc2);
      acc3 = fmaf(w, bf2f((unsigned short)(u[j].y >> 16)), acc3);
    }
  }
  s_loc += __shfl_xor(s_loc, 8);
  s_loc += __shfl_xor(s_loc, 16);
  s_loc += __shfl_xor(s_loc, 32);
  const float inv_s = 1.f / (s_loc + 1e-16f);
  const float inv_sB = __shfl(inv_s, hB);  // lane hB holds s for head hB (its hA == hB)
  acc0 *= inv_sB; acc1 *= inv_sB; acc2 *= inv_sB; acc3 *= inv_sB;
  const int col = hB * 32 + cB;
  float av[4] = {acc0, acc1, acc2, acc3};
  float tp0 = 0.f, tp1 = 0.f;
  for (int j = 0; j < 4; ++j) {
    float v = av[j] + b1[col + j];
    v = v > 0.f ? v : (__expf(v) - 1.f);  // ELU
    tp0 = fmaf(v, W2[(col + j) * 2 + 0], tp0);
    tp1 = fmaf(v, W2[(col + j) * 2 + 1], tp1);
  }
  for (int off = 32; off >= 1; off >>= 1) {
    tp0 += __shfl_xor(tp0, off);
    tp1 += __shfl_xor(tp1, off);
  }
  if (lane == 0) {
    float s2v = tp0 * a2s[0] + tp1 * a2s[1];
    float d2v = tp0 * a2d[0] + tp1 * a2d[1];
    nd[dst] = (float4){tp0, tp1, s2v, d2v};  // packed node table for agg2
  }
}

// ---------------- Layer-2 aggregation: 8 lanes per dst, packed float4 gathers (r16 proven form) ----------------
__global__ __launch_bounds__(256) void k_agg2(
    const int* __restrict__ row_ptr, const int* __restrict__ ssrc,
    const float4* __restrict__ nd, const float* __restrict__ b2,
    float* __restrict__ out) {
  int gid = blockIdx.x * 256 + threadIdx.x;
  int n = gid >> 3;
  int l8 = threadIdx.x & 7;
  if (n >= NN) return;
  int st = row_ptr[n], en = row_ptr[n + 1];
  float dv = nd[n].w;
  float ssum = 0.f, o0 = 0.f, o1 = 0.f;
  for (int e = st + l8; e < en; e += 8) {
    int s = ssrc[e];
    float4 v = nd[s];
    float w = __expf(lrelu(v.z + dv));
    ssum += w;
    o0 = fmaf(w, v.x, o0);
    o1 = fmaf(w, v.y, o1);
  }
  ssum += __shfl_xor(ssum, 1); o0 += __shfl_xor(o0, 1); o1 += __shfl_xor(o1, 1);
  ssum += __shfl_xor(ssum, 2); o0 += __shfl_xor(o0, 2); o1 += __shfl_xor(o1, 2);
  ssum += __shfl_xor(ssum, 4); o0 += __shfl_xor(o0, 4); o1 += __shfl_xor(o1, 4);
  if (l8 == 0) {
    float inv = 1.f / (ssum + 1e-16f);
    out[(size_t)n * 2 + 0] = o0 * inv + b2[0];
    out[(size_t)n * 2 + 1] = o1 * inv + b2[1];
  }
}

extern "C" void kernel_launch(void* const* d_in, const int* in_sizes, int n_in,
                              void* d_out, int out_size, void* d_ws, size_t ws_size,
                              hipStream_t stream) {
  const float* x = (const float*)d_in[0];
  const int* ei = (const int*)d_in[1];
  // d_in[2] = batch (unused)
  const float* W1 = (const float*)d_in[3];
  const float* a1s = (const float*)d_in[4];
  const float* a1d = (const float*)d_in[5];
  const float* b1 = (const float*)d_in[6];
  const float* W2 = (const float*)d_in[7];
  const float* a2s = (const float*)d_in[8];
  const float* a2d = (const float*)d_in[9];
  const float* b2 = (const float*)d_in[10];
  float* out = (float*)d_out;

  char* ws = (char*)d_ws;
  size_t off = 0;
  auto alloc = [&](size_t bytes) -> void* {
    void* p = ws + off;
    off += (bytes + 255) & ~(size_t)255;
    return p;
  };
  int* gcount = (int*)alloc((size_t)NB * 4);
  int* tmp = (int*)alloc((size_t)NB * CAP * 4);
  int* row_ptr = (int*)alloc((size_t)(NN + 1) * 4);
  int* ssrc = (int*)alloc((size_t)ET * 4);
  unsigned short* xh = (unsigned short*)alloc((size_t)NP * 128 * 2);
  unsigned short* wh = (unsigned short*)alloc((size_t)32768 * 2);
  unsigned short* h1 = (unsigned short*)alloc((size_t)NN * 256 * 2);
  float* as1 = (float*)alloc((size_t)NN * 8 * 4);
  float* ad1 = (float*)alloc((size_t)NN * 8 * 4);
  float4* nd = (float4*)alloc((size_t)NN * 16);
  (void)ws_size; (void)in_sizes; (void)n_in; (void)out_size;

  hipMemsetAsync(gcount, 0, (size_t)NB * 4, stream);
  k_front<<<FRONT_B, 1024, 0, stream>>>(ei, gcount, tmp, W1, wh, x, xh);
  k_mid<<<MID_B, 256, 0, stream>>>(tmp, gcount, ssrc, row_ptr, xh, wh, a1s, a1d, h1, as1, ad1);
  k_agg1<<<(NN + 3) / 4, 256, 0, stream>>>(row_ptr, ssrc, h1, as1, ad1, b1, W2, a2s, a2d, nd);
  k_agg2<<<(NN * 8 + 255) / 256, 256, 0, stream>>>(row_ptr, ssrc, nd, b2, out);
}